// Round 5
// baseline (154.330 us; speedup 1.0000x reference)
//
#include <hip/hip_runtime.h>

// apply_cdna_kernels: out[n,b,c,h,w] = sum_{kh,kw} images[b,h+kh-2,w+kw-2,c] * kernels[b,kh,kw,n]
// images: [64,128,128,3] f32   kernels: [64,5,5,10] f32   out: [10,64,3,128,128] f32
// Tile 8x64 px, 256 threads, 2 w-px/thread. PLANAR per-channel LDS:
// compute reads are ds_read_b64 at 8B lane stride -> 2-way bank alias = free.

#define B_  64
#define H_  128
#define W_  128
#define C_  3
#define N_  10
#define KH_ 5
#define KW_ 5
#define TH_ 8
#define TWB 64                    // tile width in pixels (2 per thread)
#define HALO 2
#define TROWS (TH_ + 2*HALO)      // 12
#define TCOLS (TWB + 2*HALO)      // 68
#define PROW  70                  // padded row stride (even -> 8B-aligned rows)
#define PLANE (TROWS * PROW)      // 840 floats per channel plane
#define LDS_ELEMS (C_ * PLANE)    // 2520 floats (10.1 KB)
#define GROW  (TCOLS * C_)        // 204 interleaved floats per staged row

typedef float f2_t __attribute__((ext_vector_type(2)));  // native vec for nontemporal store

__global__ __launch_bounds__(256, 4) void cdna_apply_kernel(
    const float* __restrict__ images,
    const float* __restrict__ kernels,
    float* __restrict__ out)
{
    __shared__ float s_img[LDS_ELEMS];

    const int tid = threadIdx.x;
    const int bid = blockIdx.x;
    const int b   = bid >> 5;          // 32 tiles per batch image
    const int t   = bid & 31;
    const int by  = t >> 1;            // 16 tiles in H
    const int bx  = t & 1;             // 2 tiles in W
    const int y0  = by * TH_;
    const int x0  = bx * TWB;

    // ---- stage image tile into planar LDS (de-interleave channels) ----
    const long img_base = (long)b * (H_ * W_ * C_);
    const int  colf0    = x0 * C_ - HALO * C_;     // first global float col (may be <0)
    #pragma unroll
    for (int k = 0; k < (TROWS * GROW + 255) / 256; ++k) {
        int g = tid + k * 256;
        if (g < TROWS * GROW) {
            int yy = g / GROW;                     // const divisor -> magic mul
            int r  = g - yy * GROW;
            int x  = r / C_;                       // tile col (pixel)
            int c  = r - x * C_;
            int y  = y0 + yy - HALO;
            int cf = colf0 + r;                    // global float column
            float v = 0.0f;
            if ((unsigned)y < (unsigned)H_ && (unsigned)cf < (unsigned)(W_ * C_))
                v = images[img_base + (long)y * (W_ * C_) + cf];
            s_img[c * PLANE + yy * PROW + x] = v;
        }
    }
    __syncthreads();

    const int tx = tid & 31;           // 32 threads per row, 2 adjacent px each
    const int ty = tid >> 5;           // 8 rows

    const float* __restrict__ kb = kernels + b * (KH_ * KW_ * N_);

    float acc0[N_ * C_];               // pixel w = x0 + 2*tx
    float acc1[N_ * C_];               // pixel w = x0 + 2*tx + 1
    #pragma unroll
    for (int i = 0; i < N_ * C_; ++i) { acc0[i] = 0.0f; acc1[i] = 0.0f; }

    // Runtime kh loop bounds the live set: 18 px regs + 60 accs + weights.
    #pragma unroll 1
    for (int kh = 0; kh < KH_; ++kh) {
        // per channel: 6 contiguous floats (cols 2tx-2 .. 2tx+3), 8B-aligned,
        // lane stride 8B -> 2-way bank alias (free). 3x ds_read_b64 each.
        float p[C_][KW_ + 1];
        #pragma unroll
        for (int c = 0; c < C_; ++c) {
            const float* row = &s_img[c * PLANE + (ty + kh) * PROW + 2 * tx];
            #pragma unroll
            for (int j = 0; j < KW_ + 1; ++j) p[c][j] = row[j];
        }

        const float* __restrict__ wrow = kb + kh * (KW_ * N_);  // uniform -> s_load
        #pragma unroll
        for (int kw = 0; kw < KW_; ++kw) {
            #pragma unroll
            for (int n = 0; n < N_; ++n) {
                const float wgt = wrow[kw * N_ + n];
                #pragma unroll
                for (int c = 0; c < C_; ++c) {
                    acc0[n * C_ + c] = fmaf(p[c][kw],     wgt, acc0[n * C_ + c]);
                    acc1[n * C_ + c] = fmaf(p[c][kw + 1], wgt, acc1[n * C_ + c]);
                }
            }
        }
    }

    // ---- write out: out[n,b,c,h,w], nontemporal float2, coalesced in w ----
    const int h = y0 + ty;
    const int w = x0 + 2 * tx;
    float* ob = out + (long)b * (C_ * H_ * W_) + (long)h * W_ + w;   // 8B aligned
    #pragma unroll
    for (int n = 0; n < N_; ++n) {
        #pragma unroll
        for (int c = 0; c < C_; ++c) {
            f2_t v;
            v.x = acc0[n * C_ + c];
            v.y = acc1[n * C_ + c];
            __builtin_nontemporal_store(
                v, (f2_t*)(ob + (long)n * ((long)B_ * C_ * H_ * W_)
                              + (long)c * (H_ * W_)));
        }
    }
}

extern "C" void kernel_launch(void* const* d_in, const int* in_sizes, int n_in,
                              void* d_out, int out_size, void* d_ws, size_t ws_size,
                              hipStream_t stream) {
    const float* images  = (const float*)d_in[0];
    const float* kernels = (const float*)d_in[1];
    float* out = (float*)d_out;

    const int grid = B_ * (H_ / TH_) * (W_ / TWB);  // 64 * 16 * 2 = 2048
    cdna_apply_kernel<<<grid, 256, 0, stream>>>(images, kernels, out);
}